// Round 3
// baseline (5185.656 us; speedup 1.0000x reference)
//
#include <hip/hip_runtime.h>
#include <stdint.h>

#define T_ 1024
#define B_ 64
#define I_ 256
#define H_ 512
#define O_ 5
#define NB 16            // batches per chain
#define NCHAIN 4
#define JW 16            // hidden columns per WG
#define GRID_MAIN 128    // 4 chains x 32 WGs
#define BLOCK_MAIN 256
#define XBS 264          // xbuf row stride in u16 (256 + 8 pad)
#define BH (B_*H_)
#define TBO (T_*B_*O_)

typedef __bf16 bf16x8 __attribute__((ext_vector_type(8)));
typedef float floatx4 __attribute__((ext_vector_type(4)));
typedef unsigned short u16;
typedef unsigned short u16x8 __attribute__((ext_vector_type(8)));
typedef unsigned int u32;
typedef unsigned long long u64;

__device__ __forceinline__ u16 f2bf(float f) {
  unsigned int u = __float_as_uint(f);
  u += 0x7fffu + ((u >> 16) & 1u);   // RNE
  return (u16)(u >> 16);
}
__device__ __forceinline__ float bf2f(u16 v) {
  return __uint_as_float(((unsigned int)v) << 16);
}
__device__ __forceinline__ float sigmoid_f(float x) {
  return 1.0f / (1.0f + __expf(-x));
}
__device__ __forceinline__ float tanh_f(float x) {
  return 2.0f / (1.0f + __expf(-2.0f * x)) - 1.0f;
}

// stage bf16(x[ts]) slice for this chain into LDS xbuf slot; u in [0,128)
__device__ __forceinline__ void stage_x(const float* __restrict__ xsrc,
                                        u16 (*xb)[XBS], int u) {
  #pragma unroll
  for (int i = 0; i < 4; ++i) {
    int cid = u + 128 * i;          // 512 chunks of 8 floats
    int b  = cid >> 5;
    int ko = (cid & 31) * 8;
    const float4* s = (const float4*)(xsrc + (size_t)b * I_ + ko);
    float4 f0 = s[0], f1 = s[1];
    u16x8 uu;
    uu[0]=f2bf(f0.x); uu[1]=f2bf(f0.y); uu[2]=f2bf(f0.z); uu[3]=f2bf(f0.w);
    uu[4]=f2bf(f1.x); uu[5]=f2bf(f1.y); uu[6]=f2bf(f1.z); uu[7]=f2bf(f1.w);
    *(u16x8*)&xb[b][ko] = uu;
  }
}

// Persistent LSTM. 4 chains (16 batches) x 32 WGs; W register-resident as bf16
// MFMA A-frags. h exchange: TAGGED u32 words ((t+1)<<16 | bf16(h)) in a 2-slot
// ping-pong buffer, relaxed agent-scope (L3-coherent) — readiness is fused into
// the payload load (no flags, no fences, no separate poll RT). x is pre-staged
// to LDS by waves 2,3 during the elementwise phase (off the critical path).
// Slot reuse (distance 2) is WAR-safe: publishing tag t+2 requires having read
// the full j-range of tag t+1, which requires every WG to have published t+1,
// which requires all of tag t to have been consumed.
__global__ __launch_bounds__(BLOCK_MAIN, 1)
void lstm_persistent(const float* __restrict__ x,
                     const float* __restrict__ W_ih,
                     const float* __restrict__ W_hh,
                     const float* __restrict__ b_ih,
                     const float* __restrict__ b_hh,
                     float* __restrict__ out,
                     u32* __restrict__ ex,      // [2][B_][H_] tagged
                     u16* __restrict__ hist)    // [(T_+1)][B_][H_] bf16
{
  __shared__ __align__(16) u16 xbuf[2][NB][XBS];
  __shared__ float part[4 * 4 * 16 * 17];       // [w][gate][j16][b(+pad)]

  const int tid   = threadIdx.x;
  const int wg    = blockIdx.x;
  const int chain = wg >> 5;
  const int jbase = (wg & 31) * JW;
  const int bbase = chain * NB;
  const int w     = tid >> 6;       // wave id = K-quarter (K-chunk range w*6..w*6+5)
  const int lane  = tid & 63;
  const int q     = lane >> 4;
  const int n     = lane & 15;

  // ---- W -> register A-fragments (A[m=lane&15][k=q*8+i]), once ----
  bf16x8 afrag[4][6];
  #pragma unroll
  for (int g = 0; g < 4; ++g) {
    #pragma unroll
    for (int kk = 0; kk < 6; ++kk) {
      const int kc  = w * 6 + kk;                 // K-chunk of 32
      const int row = g * H_ + jbase + n;         // gate row in [0,2048)
      const float* src;
      if (kc < 8) src = W_ih + (size_t)row * I_ + kc * 32 + q * 8;
      else        src = W_hh + (size_t)row * H_ + (kc - 8) * 32 + q * 8;
      float4 f0 = ((const float4*)src)[0];
      float4 f1 = ((const float4*)src)[1];
      bf16x8 a;
      a[0]=(__bf16)f0.x; a[1]=(__bf16)f0.y; a[2]=(__bf16)f0.z; a[3]=(__bf16)f0.w;
      a[4]=(__bf16)f1.x; a[5]=(__bf16)f1.y; a[6]=(__bf16)f1.z; a[7]=(__bf16)f1.w;
      afrag[g][kk] = a;
    }
  }

  // ---- elementwise identity: threads 0..127 each own (eb, j0..j0+1) ----
  const int eb = tid >> 3;          // batch within chain (0..15)
  const int j0 = (tid & 7) * 2;     // j pair within WG
  float bias2[2][4];
  float c2[2] = {0.0f, 0.0f};
  if (tid < 128) {
    #pragma unroll
    for (int jj = 0; jj < 2; ++jj)
      #pragma unroll
      for (int g = 0; g < 4; ++g) {
        const int row = g * H_ + jbase + j0 + jj;
        bias2[jj][g] = b_ih[row] + b_hh[row];
      }
  }

  // how many of my 6 K-chunks are x-chunks (the rest are h)
  const int nx = (w == 0) ? 6 : ((w == 1) ? 2 : 0);

  // ---- pre-stage x_0 ----
  if (tid >= 128) stage_x(x + (size_t)bbase * I_, xbuf[0], tid - 128);
  __syncthreads();

  for (int t = 0; t < T_; ++t) {
    const int sr = t & 1, sw = (t + 1) & 1;

    bf16x8 bfrag[6];
    // x-chunks from LDS (waves 0,1) — staged during the previous step
    #pragma unroll
    for (int kk = 0; kk < 6; ++kk) {
      if (kk < nx) {
        const int kc = w * 6 + kk;
        bfrag[kk] = __builtin_bit_cast(bf16x8,
            *(const uint4*)&xbuf[sr][n][kc * 32 + q * 8]);
      }
    }

    // h-chunks: tagged loads, retry until tag == t (readiness fused in payload)
    if (w > 0) {
      const u32* exs = ex + (size_t)sr * BH;
      const u64 tp = ((u64)(u32)t << 16) | ((u64)(u32)t << 48);
      u32 pend = 0x3Fu & ~((1u << nx) - 1u);     // chunk bits nx..5
      for (;;) {
        #pragma unroll
        for (int kk = 0; kk < 6; ++kk) {
          if ((pend >> kk) & 1u) {
            const int kc = w * 6 + kk;
            const u64* p = (const u64*)(exs + (size_t)(bbase + n) * H_ +
                                        (kc * 32 - 256) + q * 8);
            u64 r0 = __hip_atomic_load(p + 0, __ATOMIC_RELAXED, __HIP_MEMORY_SCOPE_AGENT);
            u64 r1 = __hip_atomic_load(p + 1, __ATOMIC_RELAXED, __HIP_MEMORY_SCOPE_AGENT);
            u64 r2 = __hip_atomic_load(p + 2, __ATOMIC_RELAXED, __HIP_MEMORY_SCOPE_AGENT);
            u64 r3 = __hip_atomic_load(p + 3, __ATOMIC_RELAXED, __HIP_MEMORY_SCOPE_AGENT);
            u64 bad = ((r0 ^ tp) | (r1 ^ tp) | (r2 ^ tp) | (r3 ^ tp))
                      & 0xFFFF0000FFFF0000ULL;
            if (bad == 0) {
              u32 p0 = (u32)(r0 & 0xFFFF) | ((u32)(r0 >> 16) & 0xFFFF0000u);
              u32 p1 = (u32)(r1 & 0xFFFF) | ((u32)(r1 >> 16) & 0xFFFF0000u);
              u32 p2 = (u32)(r2 & 0xFFFF) | ((u32)(r2 >> 16) & 0xFFFF0000u);
              u32 p3 = (u32)(r3 & 0xFFFF) | ((u32)(r3 >> 16) & 0xFFFF0000u);
              uint4 pk = make_uint4(p0, p1, p2, p3);
              bfrag[kk] = __builtin_bit_cast(bf16x8, pk);
              pend &= ~(1u << kk);
            }
          }
        }
        if (!__any((int)(pend != 0u))) break;
        __builtin_amdgcn_s_sleep(1);
      }
    }

    // ---- MFMA partial gates over this wave's K-quarter ----
    floatx4 acc[4] = {};
    #pragma unroll
    for (int kk = 0; kk < 6; ++kk) {
      #pragma unroll
      for (int g = 0; g < 4; ++g)
        acc[g] = __builtin_amdgcn_mfma_f32_16x16x32_bf16(afrag[g][kk], bfrag[kk], acc[g], 0, 0, 0);
    }

    // write partial C tiles (C: col=lane&15=batch, row=q*4+reg=j)
    #pragma unroll
    for (int g = 0; g < 4; ++g)
      #pragma unroll
      for (int r = 0; r < 4; ++r)
        part[((w * 4 + g) * 16 + (q * 4 + r)) * 17 + n] = acc[g][r];
    __syncthreads();

    if (tid < 128) {
      // ---- elementwise: reduce 4 K-partials, gates -> c,h ; publish tagged h ----
      float hv2[2];
      #pragma unroll
      for (int jj = 0; jj < 2; ++jj) {
        float gate[4];
        #pragma unroll
        for (int g = 0; g < 4; ++g) {
          float s = bias2[jj][g];
          #pragma unroll
          for (int w2 = 0; w2 < 4; ++w2)
            s += part[((w2 * 4 + g) * 16 + (j0 + jj)) * 17 + eb];
          gate[g] = s;
        }
        const float ig = sigmoid_f(gate[0]);
        const float fg = sigmoid_f(gate[1]);
        const float gg = tanh_f(gate[2]);
        const float og = sigmoid_f(gate[3]);
        c2[jj] = fg * c2[jj] + ig * gg;
        hv2[jj] = og * tanh_f(c2[jj]);
      }
      const int bg = bbase + eb;
      const int jg = jbase + j0;
      const u32 tag = ((u32)(t + 1)) << 16;
      const u32 w0 = tag | (u32)f2bf(hv2[0]);
      const u32 w1 = tag | (u32)f2bf(hv2[1]);
      __hip_atomic_store((u64*)(ex + (size_t)sw * BH + (size_t)bg * H_ + jg),
                         ((u64)w1 << 32) | (u64)w0,
                         __ATOMIC_RELAXED, __HIP_MEMORY_SCOPE_AGENT);
      // bf16 history for the FC pass (plain store; kernel-boundary coherence)
      *(u32*)(hist + (size_t)(t + 1) * BH + (size_t)bg * H_ + jg) =
          (u32)f2bf(hv2[0]) | ((u32)f2bf(hv2[1]) << 16);
      if (t == T_ - 1) {
        out[TBO + (size_t)bg * H_ + jg]          = hv2[0];   // h_T
        out[TBO + (size_t)bg * H_ + jg + 1]      = hv2[1];
        out[TBO + BH + (size_t)bg * H_ + jg]     = c2[0];    // c_T
        out[TBO + BH + (size_t)bg * H_ + jg + 1] = c2[1];
      }
    } else {
      // ---- waves 2,3: pre-stage x_{t+1} into the other xbuf slot ----
      const int ts = (t + 1 < T_) ? (t + 1) : (T_ - 1);
      stage_x(x + ((size_t)ts * B_ + bbase) * I_, xbuf[sw], tid - 128);
    }
    __syncthreads();   // protects part[] WAR and xbuf slot for next iteration
  }
}

// outputs[t,b,:] = h_t @ fc_w^T + fc_b ; one wave per (t,b) row
__global__ __launch_bounds__(256)
void fc_kernel(const u16* __restrict__ hist,
               const float* __restrict__ fc_w,
               const float* __restrict__ fc_b,
               float* __restrict__ out)
{
  const int gw   = (blockIdx.x * 256 + threadIdx.x) >> 6;
  const int lane = threadIdx.x & 63;
  const int t = gw >> 6;
  const int b = gw & 63;
  const u16* hrow = hist + ((size_t)(t + 1) * B_ + b) * H_ + lane * 8;
  uint4 hv = *(const uint4*)hrow;
  float h[8];
  {
    u16x8 hu = __builtin_bit_cast(u16x8, hv);
    #pragma unroll
    for (int i = 0; i < 8; ++i) h[i] = bf2f(hu[i]);
  }
  float accs[O_];
  #pragma unroll
  for (int o = 0; o < O_; ++o) {
    const float* wr = fc_w + (size_t)o * H_ + lane * 8;
    float4 w0 = ((const float4*)wr)[0];
    float4 w1 = ((const float4*)wr)[1];
    accs[o] = h[0]*w0.x + h[1]*w0.y + h[2]*w0.z + h[3]*w0.w
            + h[4]*w1.x + h[5]*w1.y + h[6]*w1.z + h[7]*w1.w;
  }
  #pragma unroll
  for (int o = 0; o < O_; ++o)
    #pragma unroll
    for (int off = 32; off > 0; off >>= 1)
      accs[o] += __shfl_down(accs[o], off, 64);
  if (lane == 0) {
    #pragma unroll
    for (int o = 0; o < O_; ++o)
      out[((size_t)t * B_ + b) * O_ + o] = accs[o] + fc_b[o];
  }
}

extern "C" void kernel_launch(void* const* d_in, const int* in_sizes, int n_in,
                              void* d_out, int out_size, void* d_ws, size_t ws_size,
                              hipStream_t stream)
{
  (void)in_sizes; (void)n_in; (void)out_size; (void)ws_size;
  const float* x    = (const float*)d_in[0];
  const float* W_ih = (const float*)d_in[1];
  const float* W_hh = (const float*)d_in[2];
  const float* b_ih = (const float*)d_in[3];
  const float* b_hh = (const float*)d_in[4];
  const float* fc_w = (const float*)d_in[5];
  const float* fc_b = (const float*)d_in[6];
  float* out = (float*)d_out;

  u32* ex   = (u32*)d_ws;                         // 2*BH tagged u32 = 256 KB
  u16* hist = (u16*)((char*)d_ws + 2 * BH * 4);   // (T_+1)*BH bf16

  // zero both ex slots: slot0 = tag 0 / h0 = 0; also clears stale tags from
  // a previous replay (harness poisons ws to 0xAA, which never matches a tag)
  hipMemsetAsync(d_ws, 0, 2 * BH * 4, stream);

  lstm_persistent<<<GRID_MAIN, BLOCK_MAIN, 0, stream>>>(
      x, W_ih, W_hh, b_ih, b_hh, out, ex, hist);
  fc_kernel<<<(T_ * B_) / 4, 256, 0, stream>>>(hist, fc_w, fc_b, out);
}